// Round 2
// baseline (923.387 us; speedup 1.0000x reference)
//
#include <hip/hip_runtime.h>
#include <cstdint>
#include <cstddef>

#define NCLS   80
#define NB     16
#define NPTS   21824      // 16384+4096+1024+256+64
#define NSEL   3320       // 1000+1000+1000+256+64
#define NCAND  2000
#define MAXPER 100

__device__ __forceinline__ float sigmoidf_(float x){ return 1.0f/(1.0f+expf(-x)); }
// monotone-increasing unsigned key for f32 (finite inputs)
__device__ __forceinline__ unsigned fkey(float f){
    unsigned u = __float_as_uint(f);
    return (u & 0x80000000u) ? ~u : (u | 0x80000000u);
}

// ---------------- K1: per-point max class score (sigmoid of max logit), float4 ----------------
__global__ void k_maxscore(const float* __restrict__ c0, const float* __restrict__ c1,
                           const float* __restrict__ c2, const float* __restrict__ c3,
                           const float* __restrict__ c4, float* __restrict__ maxscore){
    const int GP = NPTS/4;                       // 5456 point-groups per image
    int g = blockIdx.x*blockDim.x + threadIdx.x;
    if (g >= NB*GP) return;
    int b = g / GP, r = (g - b*GP)*4;            // r = first point of the 4-group
    const float* cls; int n, p;
    if      (r < 16384){ cls=c0; n=16384; p=r; }
    else if (r < 20480){ cls=c1; n=4096;  p=r-16384; }
    else if (r < 21504){ cls=c2; n=1024;  p=r-20480; }
    else if (r < 21760){ cls=c3; n=256;   p=r-21504; }
    else               { cls=c4; n=64;    p=r-21760; }
    const float* base = cls + (size_t)b*NCLS*n + p;
    float4 m = make_float4(-3.4e38f,-3.4e38f,-3.4e38f,-3.4e38f);
    #pragma unroll 8
    for (int c = 0; c < NCLS; ++c){
        const float4 v = *(const float4*)(base + (size_t)c*n);
        m.x = fmaxf(m.x, v.x); m.y = fmaxf(m.y, v.y);
        m.z = fmaxf(m.z, v.z); m.w = fmaxf(m.w, v.w);
    }
    float4 s = make_float4(sigmoidf_(m.x), sigmoidf_(m.y), sigmoidf_(m.z), sigmoidf_(m.w));
    *(float4*)(maxscore + (size_t)b*NPTS + r) = s;
}

// ---------------- K2: per-(image,level) top-k point selection (radix select) ----------------
__global__ void k_select(const float* __restrict__ maxscore, int* __restrict__ sel){
    int blk = blockIdx.x; int b = blk/5, li = blk - 5*b;
    int n, k, poff, soff;
    if      (li==0){ n=16384; k=1000; poff=0;     soff=0;    }
    else if (li==1){ n=4096;  k=1000; poff=16384; soff=1000; }
    else if (li==2){ n=1024;  k=1000; poff=20480; soff=2000; }
    else if (li==3){ n=256;   k=256;  poff=21504; soff=3000; }
    else           { n=64;    k=64;   poff=21760; soff=3256; }
    const float* x = maxscore + b*NPTS + poff;
    int* out = sel + b*NSEL + soff;
    int tid = threadIdx.x, nt = blockDim.x;
    if (k == n){ for (int i=tid;i<n;i+=nt) out[i]=i; return; }

    __shared__ unsigned hist[256];
    __shared__ unsigned sh_pref; __shared__ int sh_rem;
    unsigned prefix = 0; int rem = k;
    for (int pass = 0; pass < 4; ++pass){
        int shift = 24 - 8*pass;
        for (int i=tid;i<256;i+=nt) hist[i]=0u;
        __syncthreads();
        for (int i=tid;i<n;i+=nt){
            unsigned key = fkey(x[i]);
            if (pass==0 || (key >> (shift+8)) == prefix)
                atomicAdd(&hist[(key>>shift)&255u], 1u);
        }
        __syncthreads();
        if (tid==0){
            unsigned cum=0; int d=255;
            for(;;){ unsigned cc=hist[d]; if (cum+cc >= (unsigned)rem || d==0) break; cum+=cc; --d; }
            sh_pref = (prefix<<8) | (unsigned)d; sh_rem = rem - (int)cum;
        }
        __syncthreads();
        prefix = sh_pref; rem = sh_rem;
        __syncthreads();
    }
    unsigned T = prefix; int r = rem; int base = k - r;
    __shared__ int sh_cnt, sh_tc, sh_tp;
    if (tid==0){ sh_cnt=0; sh_tc=0; sh_tp=0; }
    __syncthreads();
    for (int i=tid;i<n;i+=nt){
        unsigned key = fkey(x[i]);
        if (key > T){ out[atomicAdd(&sh_cnt,1)] = i; }
        else if (key == T){ atomicAdd(&sh_tc,1); }
    }
    __syncthreads();
    int tc = sh_tc;
    if (tc == r){
        // exact tied set: order within output irrelevant (set semantics downstream)
        for (int i=tid;i<n;i+=nt)
            if (fkey(x[i]) == T) out[base + atomicAdd(&sh_tp,1)] = i;
    } else {
        // rare: pick the r lowest-indexed tied elements (matches lax.top_k)
        __shared__ int running; __shared__ int wt[4];
        if (tid==0) running = 0;
        __syncthreads();
        int lane = tid & 63, wid = tid >> 6, nw = nt >> 6;
        for (int i0=0; i0<n; i0+=nt){
            int i = i0 + tid;
            bool f = (i < n) && (fkey(x[i]) == T);
            unsigned long long m = __ballot(f);
            if (lane==0) wt[wid] = __popcll(m);
            __syncthreads();
            int wb = 0; for (int w=0;w<wid;++w) wb += wt[w];
            int rank = running + wb + __popcll(m & ((1ull<<lane)-1ull));
            if (f && rank < r) out[base+rank] = i;
            __syncthreads();
            if (tid==0){ int tot=0; for (int w=0;w<nw;++w) tot += wt[w]; running += tot; }
            __syncthreads();
        }
    }
}

// ---------------- K3: gather selected points, decode boxes, fused thresholded scores ----------------
__global__ void k_gather(const float* __restrict__ c0, const float* __restrict__ c1,
                         const float* __restrict__ c2, const float* __restrict__ c3,
                         const float* __restrict__ c4,
                         const float* __restrict__ b0, const float* __restrict__ b1,
                         const float* __restrict__ b2, const float* __restrict__ b3,
                         const float* __restrict__ b4,
                         const float* __restrict__ t0, const float* __restrict__ t1,
                         const float* __restrict__ t2, const float* __restrict__ t3,
                         const float* __restrict__ t4,
                         const int* __restrict__ imsz, const int* __restrict__ sel,
                         float* __restrict__ boxes, float* __restrict__ finals){
    size_t i = (size_t)blockIdx.x*blockDim.x + threadIdx.x;
    const size_t total = (size_t)NB*NSEL*NCLS;
    if (i >= total) return;
    int b = (int)(i / (NSEL*NCLS));
    int r = (int)(i - (size_t)b*(NSEL*NCLS));
    int slot = r / NCLS, c = r - slot*NCLS;
    const float *cls, *bb, *ct; int n, hw, st;
    if      (slot < 1000){ cls=c0; bb=b0; ct=t0; n=16384; hw=128; st=8;   }
    else if (slot < 2000){ cls=c1; bb=b1; ct=t1; n=4096;  hw=64;  st=16;  }
    else if (slot < 3000){ cls=c2; bb=b2; ct=t2; n=1024;  hw=32;  st=32;  }
    else if (slot < 3256){ cls=c3; bb=b3; ct=t3; n=256;   hw=16;  st=64;  }
    else                 { cls=c4; bb=b4; ct=t4; n=64;    hw=8;   st=128; }
    int p = sel[b*NSEL + slot];
    float ctrn = sigmoidf_(ct[(size_t)b*n + p]);
    float sc = sigmoidf_(cls[((size_t)b*NCLS + c)*n + p]) * ctrn;
    finals[(size_t)b*NSEL*NCLS + r] = (sc > 0.05f) ? sc : 0.0f;
    if (c == 0){
        const float* base = bb + (size_t)b*4*n;
        float d0 = base[p], d1 = base[n+p], d2 = base[2*n+p], d3 = base[3*n+p];
        int py = p / hw, px = p - py*hw;
        float mx = (float)(px*st + st/2), my = (float)(py*st + st/2);
        float w = (float)imsz[b*2+1], h = (float)imsz[b*2+0];
        float x1 = fminf(fmaxf(mx - d0, 0.0f), w);
        float y1 = fminf(fmaxf(my - d1, 0.0f), h);
        float x2 = fminf(fmaxf(mx + d2, 0.0f), w);
        float y2 = fminf(fmaxf(my + d3, 0.0f), h);
        float* bo = boxes + ((size_t)b*NSEL + slot)*4;
        bo[0]=x1; bo[1]=y1; bo[2]=x2; bo[3]=y2;
    }
}

// ---------------- K4: per-image top-2000 (radix select + compaction) ----------------
__global__ void k_top(const float* __restrict__ finals, const float* __restrict__ boxes,
                      float* __restrict__ cscore, float* __restrict__ cbox,
                      int* __restrict__ clab){
    int b = blockIdx.x;
    const int n = NSEL*NCLS, k = NCAND;
    const float* x = finals + (size_t)b*n;
    int tid = threadIdx.x, nt = blockDim.x;
    __shared__ unsigned hist[256];
    __shared__ unsigned sh_pref; __shared__ int sh_rem;
    unsigned prefix = 0; int rem = k;
    for (int pass = 0; pass < 4; ++pass){
        int shift = 24 - 8*pass;
        for (int i=tid;i<256;i+=nt) hist[i]=0u;
        __syncthreads();
        for (int i=tid;i<n;i+=nt){
            unsigned key = fkey(x[i]);
            if (pass==0 || (key >> (shift+8)) == prefix)
                atomicAdd(&hist[(key>>shift)&255u], 1u);
        }
        __syncthreads();
        if (tid==0){
            unsigned cum=0; int d=255;
            for(;;){ unsigned cc=hist[d]; if (cum+cc >= (unsigned)rem || d==0) break; cum+=cc; --d; }
            sh_pref = (prefix<<8) | (unsigned)d; sh_rem = rem - (int)cum;
        }
        __syncthreads();
        prefix = sh_pref; rem = sh_rem;
        __syncthreads();
    }
    unsigned T = prefix; int r = rem; int base = k - r;
    __shared__ int sh_cnt, sh_tc, sh_tp;
    if (tid==0){ sh_cnt=0; sh_tc=0; sh_tp=0; }
    __syncthreads();
    for (int i=tid;i<n;i+=nt){
        unsigned key = fkey(x[i]);
        if (key > T){
            int pos = atomicAdd(&sh_cnt,1);
            int slot = i/NCLS, lab = i - slot*NCLS;
            int ci = b*NCAND + pos;
            cscore[ci] = x[i]; clab[ci] = lab;
            *(float4*)(cbox + (size_t)ci*4) = *(const float4*)(boxes + ((size_t)b*NSEL + slot)*4);
        } else if (key == T){ atomicAdd(&sh_tc,1); }
    }
    __syncthreads();
    int tc = sh_tc;
    if (tc == r){
        for (int i=tid;i<n;i+=nt){
            if (fkey(x[i]) == T){
                int pos = base + atomicAdd(&sh_tp,1);
                int slot = i/NCLS, lab = i - slot*NCLS;
                int ci = b*NCAND + pos;
                cscore[ci] = x[i]; clab[ci] = lab;
                *(float4*)(cbox + (size_t)ci*4) = *(const float4*)(boxes + ((size_t)b*NSEL + slot)*4);
            }
        }
    } else {
        __shared__ int running; __shared__ int wt[16];
        if (tid==0) running = 0;
        __syncthreads();
        int lane = tid & 63, wid = tid >> 6, nw = nt >> 6;
        for (int i0=0; i0<n; i0+=nt){
            int i = i0 + tid;
            bool f = (i < n) && (fkey(x[i]) == T);
            unsigned long long m = __ballot(f);
            if (lane==0) wt[wid] = __popcll(m);
            __syncthreads();
            int wb = 0; for (int w=0;w<wid;++w) wb += wt[w];
            int rank = running + wb + __popcll(m & ((1ull<<lane)-1ull));
            if (f && rank < r){
                int pos = base + rank;
                int slot = i/NCLS, lab = i - slot*NCLS;
                int ci = b*NCAND + pos;
                cscore[ci] = x[i]; clab[ci] = lab;
                *(float4*)(cbox + (size_t)ci*4) = *(const float4*)(boxes + ((size_t)b*NSEL + slot)*4);
            }
            __syncthreads();
            if (tid==0){ int tot=0; for (int w=0;w<nw;++w) tot += wt[w]; running += tot; }
            __syncthreads();
        }
    }
}

// ---------------- K5: per-image sequential NMS (100 iters), register-resident ----------------
__global__ void __launch_bounds__(256) k_nms(const float* __restrict__ cscore,
                                             const float* __restrict__ cbox,
                                             const int*   __restrict__ clab,
                                             float* __restrict__ out){
    int b = blockIdx.x, tid = threadIdx.x;
    // candidate i = k*256 + tid, k in [0,8) -> covers 2048 >= NCAND (pads zeroed)
    float s[8], x0[8], y0[8], x1[8], y1[8];
    __shared__ float lcbox[2048][4];
    __shared__ int   llab[2048];
    __shared__ float rv[4]; __shared__ int ri[4];
    __shared__ float sbx[4];
    #pragma unroll
    for (int k=0;k<8;++k){
        int i = k*256 + tid;
        if (i < NCAND){
            int ci = b*NCAND + i;
            float4 bb = *(const float4*)(cbox + (size_t)ci*4);
            int lab = clab[ci];
            float sc = cscore[ci];
            lcbox[i][0]=bb.x; lcbox[i][1]=bb.y; lcbox[i][2]=bb.z; lcbox[i][3]=bb.w;
            llab[i] = lab;
            float lo = 1025.0f * (float)lab;     // (IMG+1)*label class-offset
            s[k]=sc; x0[k]=bb.x+lo; y0[k]=bb.y+lo; x1[k]=bb.z+lo; y1[k]=bb.w+lo;
        } else {
            lcbox[i][0]=0; lcbox[i][1]=0; lcbox[i][2]=0; lcbox[i][3]=0;
            llab[i]=0;
            s[k]=0.0f; x0[k]=0; y0[k]=0; x1[k]=0; y1[k]=0;
        }
    }
    __syncthreads();
    for (int it = 0; it < MAXPER; ++it){
        // local argmax over 8 regs (tie -> lower index)
        float v = s[0]; int bi = tid;
        #pragma unroll
        for (int k=1;k<8;++k){ if (s[k] > v){ v = s[k]; bi = k*256 + tid; } }
        // wave butterfly reduce
        #pragma unroll
        for (int off=32; off>=1; off>>=1){
            float ov = __shfl_xor(v, off);
            int   oi = __shfl_xor(bi, off);
            if (ov > v || (ov == v && oi < bi)){ v = ov; bi = oi; }
        }
        if ((tid & 63) == 0){ rv[tid>>6] = v; ri[tid>>6] = bi; }
        __syncthreads();                                  // A
        float vj = rv[0]; int j = ri[0];
        #pragma unroll
        for (int w=1; w<4; ++w){
            if (rv[w] > vj || (rv[w] == vj && ri[w] < j)){ vj = rv[w]; j = ri[w]; }
        }
        if (tid == (j & 255)){
            int k = j >> 8;
            sbx[0]=x0[k]; sbx[1]=y0[k]; sbx[2]=x1[k]; sbx[3]=y1[k];
        }
        if (tid == 0){
            bool valid = vj > 0.0f;
            float* det = out + ((size_t)b*MAXPER + it)*5;
            det[0] = valid ? lcbox[j][0] : 0.0f;
            det[1] = valid ? lcbox[j][1] : 0.0f;
            det[2] = valid ? lcbox[j][2] : 0.0f;
            det[3] = valid ? lcbox[j][3] : 0.0f;
            det[4] = valid ? vj : 0.0f;
            out[NB*MAXPER*5 + b*MAXPER + it] = valid ? (float)llab[j] : -1.0f;
        }
        __syncthreads();                                  // B
        float jx0=sbx[0], jy0=sbx[1], jx1=sbx[2], jy1=sbx[3];
        float a1 = (jx1-jx0)*(jy1-jy0);
        #pragma unroll
        for (int k=0;k<8;++k){
            float lt0 = fmaxf(jx0, x0[k]), lt1 = fmaxf(jy0, y0[k]);
            float rb0 = fminf(jx1, x1[k]), rb1 = fminf(jy1, y1[k]);
            float w = fmaxf(rb0-lt0, 0.0f), h = fmaxf(rb1-lt1, 0.0f);
            float inter = w*h;
            float a2 = (x1[k]-x0[k])*(y1[k]-y0[k]);
            float iou = inter / fmaxf(a1 + a2 - inter, 1e-6f);
            if (iou >= 0.5f) s[k] = 0.0f;
        }
    }
}

extern "C" void kernel_launch(void* const* d_in, const int* in_sizes, int n_in,
                              void* d_out, int out_size, void* d_ws, size_t ws_size,
                              hipStream_t stream){
    const float *c[5], *bx[5], *ct[5];
    for (int l=0;l<5;++l){
        c[l]  = (const float*)d_in[3*l+0];
        bx[l] = (const float*)d_in[3*l+1];
        ct[l] = (const float*)d_in[3*l+2];
    }
    const int* imsz = (const int*)d_in[15];
    // workspace layout (floats), ~20.2 MB total
    float* ws       = (float*)d_ws;
    float* maxscore = ws;                                   // 349,184
    int*   sel      = (int*)(ws + 349184);                  //  53,120
    float* boxes    = ws + 349184 + 53120;                  // 212,480 (16B-aligned)
    float* finals   = boxes + 212480;                       // 4,249,600
    float* cscore   = finals + 4249600;                     //  32,000
    float* cbox     = cscore + 32000;                       // 128,000 (16B-aligned)
    int*   clab     = (int*)(cbox + 128000);                //  32,000
    float* out = (float*)d_out;

    k_maxscore<<<dim3((NB*(NPTS/4) + 255)/256), dim3(256), 0, stream>>>(
        c[0],c[1],c[2],c[3],c[4], maxscore);
    k_select<<<dim3(NB*5), dim3(256), 0, stream>>>(maxscore, sel);
    size_t total = (size_t)NB*NSEL*NCLS;
    k_gather<<<dim3((unsigned)((total + 255)/256)), dim3(256), 0, stream>>>(
        c[0],c[1],c[2],c[3],c[4],
        bx[0],bx[1],bx[2],bx[3],bx[4],
        ct[0],ct[1],ct[2],ct[3],ct[4],
        imsz, sel, boxes, finals);
    k_top<<<dim3(NB), dim3(1024), 0, stream>>>(finals, boxes, cscore, cbox, clab);
    k_nms<<<dim3(NB), dim3(256), 0, stream>>>(cscore, cbox, clab, out);
}